// Round 5
// baseline (388.716 us; speedup 1.0000x reference)
//
#include <hip/hip_runtime.h>

// Sparse 3D conv (Cin=1, Cout=16), rulebook form:
//   out[out_idx[m], c] += feats[in_idx[m]] * weight[k_idx[m], c]
//
// Two-phase: (1) latency-rich scattered work (feats gather, slot calc) done
// by a massively-parallel m-major repack kernel with no atomics, writing a
// tile-sorted packed array of {f, (loc16<<5)|k}; (2) a throughput-shaped
// main kernel per 512-row tile: coalesced stage -> flat (entry,channel)
// loop -> ds_add_f32 into LDS tile -> single coalesced writeback.
// Slot arithmetic uses only precomputed bounds (no scans):
//   tilebase[t] = sum_k (bounds[t][k] - ks[k])         (entries before tile t)
//   pos = tilebase[t] + cumk[t][k] + (m - bounds[t][k])

#define TILE 512
#define NK 27
#define CH 512          // entries staged per chunk (4 KB)
#define WS 17           // padded weight stride in LDS

__device__ __forceinline__ int lower_bound_i32(const int* __restrict__ a,
                                               int lo, int hi, int val) {
    while (lo < hi) {
        int mid = (lo + hi) >> 1;
        if (a[mid] < val) lo = mid + 1; else hi = mid;
    }
    return lo;
}

// ks[t] = first m with k_idx[m] >= t; ks[27] = M.
__global__ void k_bounds_kernel(const int* __restrict__ k_idx, int M,
                                int* __restrict__ ks) {
    int t = threadIdx.x;
    if (t <= NK) ks[t] = lower_bound_i32(k_idx, 0, M, t);
}

// bounds[t*NK + k] = first m in segment k with out_idx[m] >= min(t*TILE, n_out)
__global__ void tile_bounds_kernel(const int* __restrict__ out_idx,
                                   const int* __restrict__ ks,
                                   int* __restrict__ bounds,
                                   int num_tiles, int n_out) {
    int idx = blockIdx.x * blockDim.x + threadIdx.x;
    int total = (num_tiles + 1) * NK;
    if (idx >= total) return;
    int t = idx / NK;
    int k = idx - t * NK;
    int q = t * TILE;
    if (q > n_out) q = n_out;
    bounds[idx] = lower_bound_i32(out_idx, ks[k], ks[k + 1], q);
}

// tilebase[t] (t in [0,num_tiles]) and per-tile exclusive k-prefix cumk.
__global__ void tile_meta_kernel(const int* __restrict__ bounds,
                                 const int* __restrict__ ks,
                                 int* __restrict__ cumk,
                                 int* __restrict__ tilebase,
                                 int num_tiles) {
    int t = blockIdx.x * blockDim.x + threadIdx.x;
    if (t > num_tiles) return;
    int tb = 0;
    for (int k = 0; k < NK; ++k) tb += bounds[t * NK + k] - ks[k];
    tilebase[t] = tb;
    if (t < num_tiles) {
        int s = 0;
        for (int k = 0; k < NK; ++k) {
            cumk[t * NK + k] = s;
            s += bounds[(t + 1) * NK + k] - bounds[t * NK + k];
        }
    }
}

// m-major: gather feats, compute packed slot, write {f, code}. No atomics.
__global__ void repack_kernel(const float* __restrict__ feats,
                              const int* __restrict__ in_idx,
                              const int* __restrict__ out_idx,
                              const int* __restrict__ k_idx,
                              const int* __restrict__ bounds,
                              const int* __restrict__ cumk,
                              const int* __restrict__ tilebase,
                              uint2* __restrict__ pack, int M) {
    int m = blockIdx.x * blockDim.x + threadIdx.x;
    if (m >= M) return;
    int k = k_idx[m];
    int o = out_idx[m];
    int i = in_idx[m];
    int t = o >> 9;                       // TILE = 512
    int lo = bounds[t * NK + k];
    int pos = tilebase[t] + cumk[t * NK + k] + (m - lo);
    uint2 p;
    p.x = __float_as_uint(feats[i]);
    p.y = ((unsigned)(o & (TILE - 1)) << 9) | (unsigned)k;  // (loc16<<5)|k
    pack[pos] = p;
}

__global__ __launch_bounds__(256, 4) void sparse_conv_flat(
    const float* __restrict__ weight,
    const uint2* __restrict__ pack,
    const int* __restrict__ tilebase,
    float* __restrict__ out, int n_out) {
    __shared__ float tile[TILE * 16];     // 32 KB
    __shared__ uint2 stage[CH];           // 4 KB
    __shared__ float w_s[NK * WS];        // padded: spreads banks
    __shared__ int base_s[2];

    const int tid = threadIdx.x;
    const int tb = blockIdx.x;
    const int o0 = tb * TILE;
    const int rows = min(TILE, n_out - o0);

    float4* t4 = (float4*)tile;
    for (int i = tid; i < TILE * 4; i += 256)
        t4[i] = make_float4(0.f, 0.f, 0.f, 0.f);
    for (int i = tid; i < NK * 16; i += 256)
        w_s[(i >> 4) * WS + (i & 15)] = weight[i];
    if (tid < 2) base_s[tid] = tilebase[tb + tid];
    __syncthreads();

    const int b0 = base_s[0];
    const int E = base_s[1] - base_s[0];
    const int c = tid & 15;               // channel fixed per thread

    for (int c0 = 0; c0 < E; c0 += CH) {
        int cnt = min(CH, E - c0);
        for (int i = tid; i < cnt; i += 256)
            stage[i] = pack[b0 + c0 + i];
        __syncthreads();
        for (int wi = tid; wi < cnt * 16; wi += 256) {
            int e = wi >> 4;
            uint2 p = stage[e];           // 16-lane broadcast
            float f = __uint_as_float(p.x);
            int code = (int)p.y;
            int loc = code >> 5;          // row*16
            int k = code & 31;
            atomicAdd(&tile[loc + c], f * w_s[k * WS + c]);  // ds_add_f32
        }
        __syncthreads();
    }

    float4* out4 = (float4*)(out + (size_t)o0 * 16);
    for (int i = tid; i < rows * 4; i += 256)
        out4[i] = t4[i];
}

// Fallback if workspace is too small: simple scatter with global atomics.
__global__ void scatter_fallback(const float* __restrict__ feats,
                                 const float* __restrict__ weight,
                                 const int* __restrict__ in_idx,
                                 const int* __restrict__ out_idx,
                                 const int* __restrict__ k_idx,
                                 float* __restrict__ out, int M) {
    long long t = (long long)blockIdx.x * blockDim.x + threadIdx.x;
    int m = (int)(t >> 4), c = (int)(t & 15);
    if (m >= M) return;
    atomicAdd(out + (long long)out_idx[m] * 16 + c,
              feats[in_idx[m]] * weight[k_idx[m] * 16 + c]);
}

extern "C" void kernel_launch(void* const* d_in, const int* in_sizes, int n_in,
                              void* d_out, int out_size, void* d_ws, size_t ws_size,
                              hipStream_t stream) {
    const float* feats   = (const float*)d_in[0];
    const float* weight  = (const float*)d_in[1];
    const int*   in_idx  = (const int*)d_in[2];
    const int*   out_idx = (const int*)d_in[3];
    const int*   k_idx   = (const int*)d_in[4];
    float*       out     = (float*)d_out;

    const int M = in_sizes[2];
    const int n_out = out_size / 16;
    const int num_tiles = (n_out + TILE - 1) / TILE;

    // Workspace layout: pack (8B aligned) first, then int arrays.
    uint2* pack    = (uint2*)d_ws;
    int*   ks      = (int*)(pack + M);                 // 32
    int*   bounds  = ks + 32;                          // (nt+1)*NK
    int*   cumk    = bounds + (size_t)(num_tiles + 1) * NK;  // nt*NK
    int*   tilebase= cumk + (size_t)num_tiles * NK;    // nt+1
    const size_t need = (size_t)(tilebase + num_tiles + 1) - (size_t)d_ws;

    if (ws_size < need) {
        hipMemsetAsync(d_out, 0, (size_t)out_size * sizeof(float), stream);
        long long total = (long long)M * 16;
        scatter_fallback<<<(int)((total + 255) / 256), 256, 0, stream>>>(
            feats, weight, in_idx, out_idx, k_idx, out, M);
        return;
    }

    k_bounds_kernel<<<1, 32, 0, stream>>>(k_idx, M, ks);

    int total_b = (num_tiles + 1) * NK;
    tile_bounds_kernel<<<(total_b + 255) / 256, 256, 0, stream>>>(
        out_idx, ks, bounds, num_tiles, n_out);

    tile_meta_kernel<<<(num_tiles + 1 + 255) / 256, 256, 0, stream>>>(
        bounds, ks, cumk, tilebase, num_tiles);

    repack_kernel<<<(M + 255) / 256, 256, 0, stream>>>(
        feats, in_idx, out_idx, k_idx, bounds, cumk, tilebase, pack, M);

    sparse_conv_flat<<<num_tiles, 256, 0, stream>>>(
        weight, pack, tilebase, out, n_out);
}